// Round 7
// baseline (767.093 us; speedup 1.0000x reference)
//
#include <hip/hip_runtime.h>

// ---------------- conv1 (3x3, 1->32, SAME) + relu + maxpool2 ----------------
// in : (32,128,128,1)  out: pool1 (32,64,64,32) NHWC flat
__global__ void k_conv1_pool(const float* __restrict__ x, const float* __restrict__ w,
                             const float* __restrict__ bias, float* __restrict__ out) {
    int t = blockIdx.x * blockDim.x + threadIdx.x;   // 32*64*64*32 = 4194304
    int c  = t & 31;
    int pw = (t >> 5) & 63;
    int ph = (t >> 11) & 63;
    int n  = t >> 17;
    float wv[9];
#pragma unroll
    for (int i = 0; i < 9; ++i) wv[i] = w[i * 32 + c];
    float b = bias[c];
    float patch[4][4];
#pragma unroll
    for (int r = 0; r < 4; ++r) {
        int gr = 2 * ph - 1 + r;
#pragma unroll
        for (int col = 0; col < 4; ++col) {
            int gc = 2 * pw - 1 + col;
            patch[r][col] = (gr >= 0 && gr < 128 && gc >= 0 && gc < 128)
                ? x[(n * 128 + gr) * 128 + gc] : 0.f;
        }
    }
    float m = 0.f;  // relu >= 0, so max-with-0 == pool(relu)
#pragma unroll
    for (int dh = 0; dh < 2; ++dh)
#pragma unroll
    for (int dw = 0; dw < 2; ++dw) {
        float s = b;
#pragma unroll
        for (int kh = 0; kh < 3; ++kh)
#pragma unroll
        for (int kw = 0; kw < 3; ++kw)
            s = fmaf(patch[dh + kh][dw + kw], wv[kh * 3 + kw], s);
        m = fmaxf(m, s);
    }
    out[t] = m;   // t == ((n*64+ph)*64+pw)*32+c
}

// ---------------- transpose conv2 weights: (kh,kw,ci,co) -> (p,ci4,co,4) -----
// R3-proven lane-coalesced layout. w2t[((p*8+ci4)*64+co)*4 + i] holds
// w2[(p*32 + ci4*4 + i)*64 + co].
__global__ void k_w2t(const float* __restrict__ w2, float* __restrict__ w2t) {
    int t = blockIdx.x * blockDim.x + threadIdx.x;   // 9*8*64*4 = 18432
    if (t >= 18432) return;
    int i   = t & 3;
    int co  = (t >> 2) & 63;
    int ci4 = (t >> 8) & 7;
    int p   = t >> 11;                // kh*3+kw
    w2t[t] = w2[(p * 32 + ci4 * 4 + i) * 64 + co];
}

// ---------------- conv2 (3x3, 32->64, SAME) + relu ---------------------------
// FMA ORDER FROZEN (R2 post-mortem: reassociation flips argmax near-ties).
// R9 restructure: WEIGHTS in LDS, INPUT via L1. R8 post-mortem arithmetic:
// each wave re-read the 72KB weight table per q-sweep (1.18GB total) through
// the L1-MISS path (table > 32KB L1) -> ~95us/CU of L2-line traffic; that
// was the wall (R7/R8 neutral: not load-count, not latency). Now: w2t staged
// once per block into 73.7KB dynamic LDS (>64KB OK on gfx950, m201 precedent)
// read as lane-linear ds_read_b128 (1KB/instr, conflict-free, ~20us/CU);
// input read direct from global — address is WAVE-UNIFORM (n,rp,q,ci4,j all
// wave-constant) -> 1-line broadcast loads, block footprint 23KB fully
// L1-resident (~10us/CU). Pipes now FMA 31 / LDS 20 / VMEM 10.
// Values bit-identical to R5/R8: weights copied verbatim; input guards
// (ir,ic in [0,64)) reproduce the old zero-filled halo exactly; per-acc
// order (kh asc via q, ci4 asc, kw asc, elem) unchanged.
__global__ void __launch_bounds__(256, 2)
k_conv2(const float* __restrict__ in, const float* __restrict__ w2t,
        const float* __restrict__ bias, float* __restrict__ out) {
    extern __shared__ float wlds[];       // 18432 floats = 73728 B
    int bid = blockIdx.x;                 // 32 n * 32 tiles = 1024
    int n = bid >> 5;
    int tile = bid & 31;
    int r0b = (tile >> 3) * 16;           // 4 row-tiles of 16
    int c0b = (tile & 7) * 8;             // 8 col-tiles of 8
    int tid = threadIdx.x;
    for (int i = tid; i < 4608; i += 256) // 4608 float4 = whole w2t table
        *(float4*)&wlds[i * 4] = *(const float4*)&w2t[i * 4];
    __syncthreads();
    int co = tid & 63;
    int rp = tid >> 6;                    // 0..3 -> out rows rp*4 .. rp*4+3
    float bb = bias[co];
    const float* wbase = wlds + co * 4;   // float4 at wbase + ((kh*3+kw)*8+ci4)*256
    float acc[4][8];
#pragma unroll
    for (int r = 0; r < 4; ++r)
#pragma unroll
        for (int c = 0; c < 8; ++c) acc[r][c] = bb;

#pragma unroll
    for (int q = 0; q < 6; ++q) {         // input row ir; serves out r with kh=q-r in [0,2]
        int ir = r0b + rp * 4 + q - 1;
        bool rok = ((unsigned)ir < 64u);
        const float* rowp = in + (((size_t)(n * 64) + ir) * 64) * 32;  // deref guarded
        for (int ci4 = 0; ci4 < 8; ++ci4) {
            float4 v[10];
#pragma unroll
            for (int j = 0; j < 10; ++j) {
                int ic = c0b - 1 + j;
                bool ok = rok && ((unsigned)ic < 64u);
                v[j] = ok ? *(const float4*)&rowp[ic * 32 + ci4 * 4]
                          : make_float4(0.f, 0.f, 0.f, 0.f);
            }
#pragma unroll
            for (int r = 0; r < 4; ++r) {
                int kh = q - r;           // compile-time after q-unroll
                if (kh < 0 || kh > 2) continue;
#pragma unroll
                for (int kw = 0; kw < 3; ++kw) {
                    float4 wv = *(const float4*)&wbase[((kh * 3 + kw) * 8 + ci4) * 256];
#pragma unroll
                    for (int c = 0; c < 8; ++c) {
                        float4 xv = v[c + kw];
                        float a = acc[r][c];
                        a = fmaf(xv.x, wv.x, a);
                        a = fmaf(xv.y, wv.y, a);
                        a = fmaf(xv.z, wv.z, a);
                        a = fmaf(xv.w, wv.w, a);
                        acc[r][c] = a;
                    }
                }
            }
        }
    }
#pragma unroll
    for (int r = 0; r < 4; ++r) {
        int gr = r0b + rp * 4 + r;
#pragma unroll
        for (int c = 0; c < 8; ++c) {
            int gc = c0b + c;
            out[((n * 64 + gr) * 64 + gc) * 64 + co] = fmaxf(acc[r][c], 0.f);
        }
    }
}

// ---------------- argmax phase A: per (n, part of 256 pos) -------------------
__global__ void k_argmax_A(const float* __restrict__ conv2, float* __restrict__ abest,
                           int* __restrict__ aidx, float* __restrict__ asum) {
    int n = blockIdx.x, part = blockIdx.y;
    int tid = threadIdx.x;
    int c = tid & 63, sub = tid >> 6;
    const float* base = conv2 + (size_t)n * 4096 * 64;
    int p0 = part * 256 + sub * 64;
    float best = -1e30f; int bi = p0; float s = 0.f;
    for (int i = 0; i < 64; ++i) {
        int p = p0 + i;
        float v = base[(size_t)p * 64 + c];
        s += v;
        if (v > best) { best = v; bi = p; }
    }
    __shared__ float sb[256], ss[256];
    __shared__ int sidx[256];
    sb[tid] = best; ss[tid] = s; sidx[tid] = bi;
    __syncthreads();
    if (sub == 0) {
        for (int pp = 1; pp < 4; ++pp) {      // ascending order -> first-occurrence
            float v = sb[pp * 64 + c];
            if (v > best) { best = v; bi = sidx[pp * 64 + c]; }
            s += ss[pp * 64 + c];
        }
        int o = (n * 16 + part) * 64 + c;
        abest[o] = best; aidx[o] = bi; asum[o] = s;
    }
}

// ---------------- argmax phase B: combine 16 parts in order ------------------
__global__ void k_argmax_B(const float* __restrict__ abest, const int* __restrict__ aidx,
                           const float* __restrict__ asum, int* __restrict__ idx,
                           float* __restrict__ psum) {
    int n = blockIdx.x;                   // 32
    int c = threadIdx.x;                  // 64
    float best = -1e30f; int bi = 0; float s = 0.f;
    for (int part = 0; part < 16; ++part) {
        int o = (n * 16 + part) * 64 + c;
        float v = abest[o];
        s += asum[o];
        if (v > best) { best = v; bi = aidx[o]; }
    }
    idx[n * 64 + c] = bi;
    psum[n * 64 + c] = s;
}

// ---------------- mask * conv2, relu, maxpool2 -> conv2_pool (32,32,32,64) ---
__global__ void k_mask_pool(const float* __restrict__ conv2, const int* __restrict__ idx,
                            float* __restrict__ out) {
    int t = blockIdx.x * blockDim.x + threadIdx.x;   // 2097152
    int c  = t & 63;
    int pw = (t >> 6) & 31;
    int ph = (t >> 11) & 31;
    int n  = t >> 16;
    int id = idx[n * 64 + c];
    float ih = (float)(id >> 6);
    float iw = (float)(id & 63);
    float m = 0.f;
#pragma unroll
    for (int dh = 0; dh < 2; ++dh) {
#pragma unroll
        for (int dw = 0; dw < 2; ++dw) {
            int h = 2 * ph + dh, w = 2 * pw + dw;
            float d = (fabsf((float)h - ih) + fabsf((float)w - iw)) * (1.0f / 31.5f);
            float mask = fmaxf(1.0f - 0.5f * d, -1.0f);
            float v = conv2[(((size_t)n * 64 + h) * 64 + w) * 64 + c] * mask;
            m = fmaxf(m, v);
        }
    }
    out[t] = m;
}

// ---------------- dense1 split-K GEMM: (32,65536)@(65536,1024) ---------------
// R9 change: k-chunk 256 -> 512 (128 chunks). xs 64KB (2 blocks/CU), partial
// buffer + its re-read shrink 33.5 -> 16.8 MB (-33MB HBM). Per-(n,j) add
// sequence still strictly k-ascending within chunk, chunk-ascending in the
// reduce -> bit-identical. R6-proven 4j x 8n thread mapping unchanged.
__global__ void __launch_bounds__(256, 4)
k_dense1_partial(const float* __restrict__ xflat,
                 const float* __restrict__ w1,
                 float* __restrict__ partial) {
    __shared__ float xs[32 * 512];        // 64 KB, [n][k]
    int chunk = blockIdx.x;               // 0..127
    int jg = blockIdx.y;                  // 0..3
    int tid = threadIdx.x;
    int k0 = chunk * 512;
    for (int i = tid; i < 4096; i += 256) {
        int n = i >> 7, kq = i & 127;
        *(float4*)&xs[n * 512 + kq * 4] =
            *(const float4*)&xflat[(size_t)n * 65536 + k0 + kq * 4];
    }
    __syncthreads();
    int g  = tid >> 6;                    // ngroup: n in [g*8, g*8+8)
    int jt = tid & 63;
    int j0 = jg * 256 + jt * 4;           // 4 consecutive j
    float acc[8][4];
#pragma unroll
    for (int n = 0; n < 8; ++n)
#pragma unroll
        for (int j = 0; j < 4; ++j) acc[n][j] = 0.f;
    const float* wp = w1 + (size_t)k0 * 1024 + j0;
    const float* xb = xs + g * 8 * 512;
    // distance-1 prefetch pipeline over k4 blocks: rows k..k+3, float4 of 4 j
    float4 wv[4], wn[4];
#pragma unroll
    for (int i = 0; i < 4; ++i) wv[i] = *(const float4*)&wp[(size_t)i * 1024];
    for (int k4 = 0; k4 < 128; ++k4) {
        int k = k4 * 4;
        int kpre = (k4 < 127) ? (k + 4) : 0;   // safe dummy on last iter
#pragma unroll
        for (int i = 0; i < 4; ++i)
            wn[i] = *(const float4*)&wp[(size_t)(kpre + i) * 1024];
#pragma unroll
        for (int n = 0; n < 8; ++n) {
            float4 xv = *(const float4*)&xb[n * 512 + k];   // broadcast, conflict-free
#pragma unroll
            for (int j = 0; j < 4; ++j) {
                float a = acc[n][j];
                // k ascending per acc element — matches R5 accumulation order
                a = fmaf(xv.x, ((const float*)&wv[0])[j], a);
                a = fmaf(xv.y, ((const float*)&wv[1])[j], a);
                a = fmaf(xv.z, ((const float*)&wv[2])[j], a);
                a = fmaf(xv.w, ((const float*)&wv[3])[j], a);
                acc[n][j] = a;
            }
        }
#pragma unroll
        for (int i = 0; i < 4; ++i) wv[i] = wn[i];
    }
#pragma unroll
    for (int n = 0; n < 8; ++n) {
        int gn = g * 8 + n;
        *(float4*)&partial[((size_t)chunk * 32 + gn) * 1024 + j0] =
            make_float4(acc[n][0], acc[n][1], acc[n][2], acc[n][3]);
    }
}

// ---------------- reduce partials + bias + relu -> dense_out (32,1024) -------
__global__ void k_dense1_reduce(const float* __restrict__ partial, const float* __restrict__ b,
                                float* __restrict__ dout) {
    int t = blockIdx.x * blockDim.x + threadIdx.x;   // 32768
    int n = t >> 10, j = t & 1023;
    float s = b[j];
    for (int ch = 0; ch < 128; ++ch)
        s += partial[((size_t)ch * 32 + n) * 1024 + j];
    dout[t] = fmaxf(s, 0.f);
}

// ---------------- dense2 -> logits (32,10) -----------------------------------
__global__ void k_dense2(const float* __restrict__ dout, const float* __restrict__ w,
                         const float* __restrict__ b, float* __restrict__ logits) {
    int bid = blockIdx.x;                 // 320 = 32 n * 10 j
    int n = bid / 10, j = bid % 10;
    int lane = threadIdx.x;               // 64
    float s = 0.f;
    for (int k = lane; k < 1024; k += 64)
        s = fmaf(dout[n * 1024 + k], w[k * 10 + j], s);
#pragma unroll
    for (int off = 32; off > 0; off >>= 1)
        s += __shfl_down(s, off);
    if (lane == 0) logits[n * 10 + j] = s + b[j];
}

// ---------------- per-category avg + argmax (np NaN-first semantics) ---------
__global__ void k_filter_cat(const float* __restrict__ psum, const int* __restrict__ labels,
                             float* __restrict__ out) {
    int c = threadIdx.x;                  // 64
    float sums[10]; int cnt[10];
#pragma unroll
    for (int i = 0; i < 10; ++i) { sums[i] = 0.f; cnt[i] = 0; }
    for (int bb = 0; bb < 32; ++bb) {
        int l = labels[bb];
        sums[l] += psum[bb * 64 + c];
        cnt[l]++;
    }
    int best_i = 0; float best = -1e30f;
    for (int i = 0; i < 10; ++i) {
        float v = sums[i] / (float)cnt[i];   // 0/0 -> NaN when category empty
        if (v != v) { best_i = i; break; }   // np.argmax: first NaN wins
        if (v > best) { best = v; best_i = i; }
    }
    out[c] = (float)best_i;
}

extern "C" void kernel_launch(void* const* d_in, const int* in_sizes, int n_in,
                              void* d_out, int out_size, void* d_ws, size_t ws_size,
                              hipStream_t stream) {
    const float* x    = (const float*)d_in[0];
    const int* labels = (const int*)d_in[1];
    const float* c1w  = (const float*)d_in[2];
    const float* c1b  = (const float*)d_in[3];
    const float* c2w  = (const float*)d_in[4];
    const float* c2b  = (const float*)d_in[5];
    const float* d1w  = (const float*)d_in[6];
    const float* d1b  = (const float*)d_in[7];
    const float* d2w  = (const float*)d_in[8];
    const float* d2b  = (const float*)d_in[9];
    float* out = (float*)d_out;
    float* ws  = (float*)d_ws;

    // workspace layout (floats).
    // partial (128*32*1024 = 4,194,304) ALIASES conv2o (dead after k_mask_pool).
    float* pool1   = ws;                       // 4,194,304  (32,64,64,32)
    float* conv2o  = ws + 4194304;             // 8,388,608  (32,64,64,64)
    float* partial = conv2o;                   // 4,194,304  (128,32,1024) - alias
    float* w2t     = ws + 12582912;            // 18,432
    int*   idx     = (int*)(ws + 12601344);    // 2,048
    float* psum    = ws + 12603392;            // 2,048
    float* abest   = ws + 12605440;            // 32,768 (32,16,64)
    int*   aidx    = (int*)(ws + 12638208);    // 32,768
    float* asum    = ws + 12670976;            // 32,768
    float* dense1o = ws + 12703744;            // 32,768 (32,1024)

    float* logits = out;                       // 320
    float* pool2  = out + 320;                 // 2,097,152  (32,32,32,64)
    float* fcat   = out + 320 + 2097152;       // 64

    k_w2t<<<72, 256, 0, stream>>>(c2w, w2t);
    k_conv1_pool<<<16384, 256, 0, stream>>>(x, c1w, c1b, pool1);
    k_conv2<<<1024, 256, 73728, stream>>>(pool1, w2t, c2b, conv2o);
    dim3 ga(32, 16);
    k_argmax_A<<<ga, 256, 0, stream>>>(conv2o, abest, aidx, asum);
    k_argmax_B<<<32, 64, 0, stream>>>(abest, aidx, asum, idx, psum);
    k_mask_pool<<<8192, 256, 0, stream>>>(conv2o, idx, pool2);
    dim3 g5(128, 4);
    k_dense1_partial<<<g5, 256, 0, stream>>>(pool2, d1w, partial);
    k_dense1_reduce<<<128, 256, 0, stream>>>(partial, d1b, dense1o);
    k_dense2<<<320, 64, 0, stream>>>(dense1o, d2w, d2b, logits);
    k_filter_cat<<<1, 64, 0, stream>>>(psum, labels, fcat);
}

// Round 8
// 536.007 us; speedup vs baseline: 1.4311x; 1.4311x over previous
//
#include <hip/hip_runtime.h>

// ---------------- conv1 (3x3, 1->32, SAME) + relu + maxpool2 ----------------
// in : (32,128,128,1)  out: pool1 (32,64,64,32) NHWC flat
__global__ void k_conv1_pool(const float* __restrict__ x, const float* __restrict__ w,
                             const float* __restrict__ bias, float* __restrict__ out) {
    int t = blockIdx.x * blockDim.x + threadIdx.x;   // 32*64*64*32 = 4194304
    int c  = t & 31;
    int pw = (t >> 5) & 63;
    int ph = (t >> 11) & 63;
    int n  = t >> 17;
    float wv[9];
#pragma unroll
    for (int i = 0; i < 9; ++i) wv[i] = w[i * 32 + c];
    float b = bias[c];
    float patch[4][4];
#pragma unroll
    for (int r = 0; r < 4; ++r) {
        int gr = 2 * ph - 1 + r;
#pragma unroll
        for (int col = 0; col < 4; ++col) {
            int gc = 2 * pw - 1 + col;
            patch[r][col] = (gr >= 0 && gr < 128 && gc >= 0 && gc < 128)
                ? x[(n * 128 + gr) * 128 + gc] : 0.f;
        }
    }
    float m = 0.f;  // relu >= 0, so max-with-0 == pool(relu)
#pragma unroll
    for (int dh = 0; dh < 2; ++dh)
#pragma unroll
    for (int dw = 0; dw < 2; ++dw) {
        float s = b;
#pragma unroll
        for (int kh = 0; kh < 3; ++kh)
#pragma unroll
        for (int kw = 0; kw < 3; ++kw)
            s = fmaf(patch[dh + kh][dw + kw], wv[kh * 3 + kw], s);
        m = fmaxf(m, s);
    }
    out[t] = m;   // t == ((n*64+ph)*64+pw)*32+c
}

// ---------------- transpose conv2 weights: (kh,kw,ci,co) -> (p,ci4,co,4) -----
// R3-proven lane-coalesced layout. w2t[((p*8+ci4)*64+co)*4 + i] holds
// w2[(p*32 + ci4*4 + i)*64 + co].
__global__ void k_w2t(const float* __restrict__ w2, float* __restrict__ w2t) {
    int t = blockIdx.x * blockDim.x + threadIdx.x;   // 9*8*64*4 = 18432
    if (t >= 18432) return;
    int i   = t & 3;
    int co  = (t >> 2) & 63;
    int ci4 = (t >> 8) & 7;
    int p   = t >> 11;                // kh*3+kw
    w2t[t] = w2[(p * 32 + ci4 * 4 + i) * 64 + co];
}

// ---------------- conv2 (3x3, 32->64, SAME) + relu ---------------------------
// FMA ORDER FROZEN (R2 post-mortem: reassociation flips argmax near-ties).
// R10: BOTH operands in LDS, paid for by co-split. R9 post-mortem: weights-in
// -LDS was right (R8 arithmetic: weight L1-miss stream ~95us/CU was the
// wall) but input-via-global-broadcast was a 480-serialized-VMEM disaster at
// 8 waves/CU. Now: block = 32x8 spatial x 32 co (half). LDS = input tile
// [34][10][32] (43.5KB) + weight half-table [72][32]f4 (36.9KB) = 80384 B
// -> 2 blocks/CU (160768 <= 163840). Inner loop touches ONLY LDS:
// input reads 2-way broadcast pairs (lanes differ only in rp, free per
// m136), weight reads broadcast pairs across co-half (conflict-free).
// Per-CU: FMA 73.7k cyc vs LDS ~61k cyc vs staging VMEM ~trivial -> FMA-
// bound. Bit-identical: verbatim weight copy, same zero-halo guards, per-acc
// order (kh asc via q, ci4 asc, kw asc, elem) unchanged.
__global__ void __launch_bounds__(256, 2)
k_conv2(const float* __restrict__ in, const float* __restrict__ w2t,
        const float* __restrict__ bias, float* __restrict__ out) {
    extern __shared__ float lds[];        // ilds[10880] + wlds[9216]
    float* ilds = lds;
    float* wlds = lds + 10880;
    int bid = blockIdx.x;                 // ((n*2+rt)*8+ct)*2+ch = 1024
    int ch = bid & 1;
    int ct = (bid >> 1) & 7;
    int rt = (bid >> 4) & 1;
    int n  = bid >> 5;
    int r0b = rt * 32;
    int c0b = ct * 8;
    int tid = threadIdx.x;
    // stage input tile rows r0b-1 .. r0b+32, cols c0b-1 .. c0b+8, all 32 ci
    for (int i4 = tid; i4 < 2720; i4 += 256) {
        int c4 = i4 & 7;
        int cr = i4 >> 3;
        int col = cr % 10;
        int row = cr / 10;                // 0..33
        int gr = r0b - 1 + row;
        int gc = c0b - 1 + col;
        float4 v = make_float4(0.f, 0.f, 0.f, 0.f);
        if ((unsigned)gr < 64u && (unsigned)gc < 64u)
            v = *(const float4*)&in[(((size_t)n * 64 + gr) * 64 + gc) * 32 + c4 * 4];
        *(float4*)&ilds[i4 * 4] = v;
    }
    // stage weight half-table: wlds f4[pc*32+coh] = w2t f4[pc*64 + ch*32 + coh]
    for (int f4 = tid; f4 < 2304; f4 += 256) {
        int coh = f4 & 31;
        int pc  = f4 >> 5;                // p*8+ci4, 0..71
        *(float4*)&wlds[f4 * 4] = *(const float4*)&w2t[(pc * 64 + ch * 32 + coh) * 4];
    }
    __syncthreads();
    int coh = tid & 31;
    int rp  = tid >> 5;                   // 0..7 -> out rows rp*4 .. rp*4+3
    int co  = ch * 32 + coh;
    float bb = bias[co];
    const float* wbase = wlds + coh * 4;  // float4 at wbase + ((kh*3+kw)*8+ci4)*128
    const float* lbase = ilds + rp * 4 * 320;
    float acc[4][8];
#pragma unroll
    for (int r = 0; r < 4; ++r)
#pragma unroll
        for (int c = 0; c < 8; ++c) acc[r][c] = bb;

#pragma unroll
    for (int q = 0; q < 6; ++q) {         // local input row rp*4+q; kh=q-r in [0,2]
        for (int ci4 = 0; ci4 < 8; ++ci4) {
            float4 v[10];
#pragma unroll
            for (int j = 0; j < 10; ++j)
                v[j] = *(const float4*)&lbase[q * 320 + j * 32 + ci4 * 4];
#pragma unroll
            for (int r = 0; r < 4; ++r) {
                int kh = q - r;           // compile-time after unroll
                if (kh < 0 || kh > 2) continue;
#pragma unroll
                for (int kw = 0; kw < 3; ++kw) {
                    float4 wv = *(const float4*)&wbase[((kh * 3 + kw) * 8 + ci4) * 128];
#pragma unroll
                    for (int c = 0; c < 8; ++c) {
                        float4 xv = v[c + kw];
                        float a = acc[r][c];
                        a = fmaf(xv.x, wv.x, a);
                        a = fmaf(xv.y, wv.y, a);
                        a = fmaf(xv.z, wv.z, a);
                        a = fmaf(xv.w, wv.w, a);
                        acc[r][c] = a;
                    }
                }
            }
        }
    }
#pragma unroll
    for (int r = 0; r < 4; ++r) {
        int gr = r0b + rp * 4 + r;
#pragma unroll
        for (int c = 0; c < 8; ++c) {
            int gc = c0b + c;
            out[((n * 64 + gr) * 64 + gc) * 64 + co] = fmaxf(acc[r][c], 0.f);
        }
    }
}

// ---------------- argmax phase A: per (n, part of 256 pos) -------------------
__global__ void k_argmax_A(const float* __restrict__ conv2, float* __restrict__ abest,
                           int* __restrict__ aidx, float* __restrict__ asum) {
    int n = blockIdx.x, part = blockIdx.y;
    int tid = threadIdx.x;
    int c = tid & 63, sub = tid >> 6;
    const float* base = conv2 + (size_t)n * 4096 * 64;
    int p0 = part * 256 + sub * 64;
    float best = -1e30f; int bi = p0; float s = 0.f;
    for (int i = 0; i < 64; ++i) {
        int p = p0 + i;
        float v = base[(size_t)p * 64 + c];
        s += v;
        if (v > best) { best = v; bi = p; }
    }
    __shared__ float sb[256], ss[256];
    __shared__ int sidx[256];
    sb[tid] = best; ss[tid] = s; sidx[tid] = bi;
    __syncthreads();
    if (sub == 0) {
        for (int pp = 1; pp < 4; ++pp) {      // ascending order -> first-occurrence
            float v = sb[pp * 64 + c];
            if (v > best) { best = v; bi = sidx[pp * 64 + c]; }
            s += ss[pp * 64 + c];
        }
        int o = (n * 16 + part) * 64 + c;
        abest[o] = best; aidx[o] = bi; asum[o] = s;
    }
}

// ---------------- argmax phase B: combine 16 parts in order ------------------
__global__ void k_argmax_B(const float* __restrict__ abest, const int* __restrict__ aidx,
                           const float* __restrict__ asum, int* __restrict__ idx,
                           float* __restrict__ psum) {
    int n = blockIdx.x;                   // 32
    int c = threadIdx.x;                  // 64
    float best = -1e30f; int bi = 0; float s = 0.f;
    for (int part = 0; part < 16; ++part) {
        int o = (n * 16 + part) * 64 + c;
        float v = abest[o];
        s += asum[o];
        if (v > best) { best = v; bi = aidx[o]; }
    }
    idx[n * 64 + c] = bi;
    psum[n * 64 + c] = s;
}

// ---------------- mask * conv2, relu, maxpool2 -> conv2_pool (32,32,32,64) ---
__global__ void k_mask_pool(const float* __restrict__ conv2, const int* __restrict__ idx,
                            float* __restrict__ out) {
    int t = blockIdx.x * blockDim.x + threadIdx.x;   // 2097152
    int c  = t & 63;
    int pw = (t >> 6) & 31;
    int ph = (t >> 11) & 31;
    int n  = t >> 16;
    int id = idx[n * 64 + c];
    float ih = (float)(id >> 6);
    float iw = (float)(id & 63);
    float m = 0.f;
#pragma unroll
    for (int dh = 0; dh < 2; ++dh) {
#pragma unroll
        for (int dw = 0; dw < 2; ++dw) {
            int h = 2 * ph + dh, w = 2 * pw + dw;
            float d = (fabsf((float)h - ih) + fabsf((float)w - iw)) * (1.0f / 31.5f);
            float mask = fmaxf(1.0f - 0.5f * d, -1.0f);
            float v = conv2[(((size_t)n * 64 + h) * 64 + w) * 64 + c] * mask;
            m = fmaxf(m, v);
        }
    }
    out[t] = m;
}

// ---------------- dense1 split-K GEMM: (32,65536)@(65536,1024) ---------------
// R9-proven: k-chunk 512 (128 chunks), xs 64KB, partial re-read 16.8MB
// (~-18us vs 256-chunk). R6-proven 4j x 8n thread mapping. Bit-identical
// add order (k asc within chunk, chunk asc in reduce).
__global__ void __launch_bounds__(256, 4)
k_dense1_partial(const float* __restrict__ xflat,
                 const float* __restrict__ w1,
                 float* __restrict__ partial) {
    __shared__ float xs[32 * 512];        // 64 KB, [n][k]
    int chunk = blockIdx.x;               // 0..127
    int jg = blockIdx.y;                  // 0..3
    int tid = threadIdx.x;
    int k0 = chunk * 512;
    for (int i = tid; i < 4096; i += 256) {
        int n = i >> 7, kq = i & 127;
        *(float4*)&xs[n * 512 + kq * 4] =
            *(const float4*)&xflat[(size_t)n * 65536 + k0 + kq * 4];
    }
    __syncthreads();
    int g  = tid >> 6;                    // ngroup: n in [g*8, g*8+8)
    int jt = tid & 63;
    int j0 = jg * 256 + jt * 4;           // 4 consecutive j
    float acc[8][4];
#pragma unroll
    for (int n = 0; n < 8; ++n)
#pragma unroll
        for (int j = 0; j < 4; ++j) acc[n][j] = 0.f;
    const float* wp = w1 + (size_t)k0 * 1024 + j0;
    const float* xb = xs + g * 8 * 512;
    // distance-1 prefetch pipeline over k4 blocks: rows k..k+3, float4 of 4 j
    float4 wv[4], wn[4];
#pragma unroll
    for (int i = 0; i < 4; ++i) wv[i] = *(const float4*)&wp[(size_t)i * 1024];
    for (int k4 = 0; k4 < 128; ++k4) {
        int k = k4 * 4;
        int kpre = (k4 < 127) ? (k + 4) : 0;   // safe dummy on last iter
#pragma unroll
        for (int i = 0; i < 4; ++i)
            wn[i] = *(const float4*)&wp[(size_t)(kpre + i) * 1024];
#pragma unroll
        for (int n = 0; n < 8; ++n) {
            float4 xv = *(const float4*)&xb[n * 512 + k];   // broadcast, conflict-free
#pragma unroll
            for (int j = 0; j < 4; ++j) {
                float a = acc[n][j];
                // k ascending per acc element — matches R5 accumulation order
                a = fmaf(xv.x, ((const float*)&wv[0])[j], a);
                a = fmaf(xv.y, ((const float*)&wv[1])[j], a);
                a = fmaf(xv.z, ((const float*)&wv[2])[j], a);
                a = fmaf(xv.w, ((const float*)&wv[3])[j], a);
                acc[n][j] = a;
            }
        }
#pragma unroll
        for (int i = 0; i < 4; ++i) wv[i] = wn[i];
    }
#pragma unroll
    for (int n = 0; n < 8; ++n) {
        int gn = g * 8 + n;
        *(float4*)&partial[((size_t)chunk * 32 + gn) * 1024 + j0] =
            make_float4(acc[n][0], acc[n][1], acc[n][2], acc[n][3]);
    }
}

// ---------------- reduce partials + bias + relu -> dense_out (32,1024) -------
__global__ void k_dense1_reduce(const float* __restrict__ partial, const float* __restrict__ b,
                                float* __restrict__ dout) {
    int t = blockIdx.x * blockDim.x + threadIdx.x;   // 32768
    int n = t >> 10, j = t & 1023;
    float s = b[j];
    for (int ch = 0; ch < 128; ++ch)
        s += partial[((size_t)ch * 32 + n) * 1024 + j];
    dout[t] = fmaxf(s, 0.f);
}

// ---------------- dense2 -> logits (32,10) -----------------------------------
__global__ void k_dense2(const float* __restrict__ dout, const float* __restrict__ w,
                         const float* __restrict__ b, float* __restrict__ logits) {
    int bid = blockIdx.x;                 // 320 = 32 n * 10 j
    int n = bid / 10, j = bid % 10;
    int lane = threadIdx.x;               // 64
    float s = 0.f;
    for (int k = lane; k < 1024; k += 64)
        s = fmaf(dout[n * 1024 + k], w[k * 10 + j], s);
#pragma unroll
    for (int off = 32; off > 0; off >>= 1)
        s += __shfl_down(s, off);
    if (lane == 0) logits[n * 10 + j] = s + b[j];
}

// ---------------- per-category avg + argmax (np NaN-first semantics) ---------
__global__ void k_filter_cat(const float* __restrict__ psum, const int* __restrict__ labels,
                             float* __restrict__ out) {
    int c = threadIdx.x;                  // 64
    float sums[10]; int cnt[10];
#pragma unroll
    for (int i = 0; i < 10; ++i) { sums[i] = 0.f; cnt[i] = 0; }
    for (int bb = 0; bb < 32; ++bb) {
        int l = labels[bb];
        sums[l] += psum[bb * 64 + c];
        cnt[l]++;
    }
    int best_i = 0; float best = -1e30f;
    for (int i = 0; i < 10; ++i) {
        float v = sums[i] / (float)cnt[i];   // 0/0 -> NaN when category empty
        if (v != v) { best_i = i; break; }   // np.argmax: first NaN wins
        if (v > best) { best = v; best_i = i; }
    }
    out[c] = (float)best_i;
}

extern "C" void kernel_launch(void* const* d_in, const int* in_sizes, int n_in,
                              void* d_out, int out_size, void* d_ws, size_t ws_size,
                              hipStream_t stream) {
    const float* x    = (const float*)d_in[0];
    const int* labels = (const int*)d_in[1];
    const float* c1w  = (const float*)d_in[2];
    const float* c1b  = (const float*)d_in[3];
    const float* c2w  = (const float*)d_in[4];
    const float* c2b  = (const float*)d_in[5];
    const float* d1w  = (const float*)d_in[6];
    const float* d1b  = (const float*)d_in[7];
    const float* d2w  = (const float*)d_in[8];
    const float* d2b  = (const float*)d_in[9];
    float* out = (float*)d_out;
    float* ws  = (float*)d_ws;

    // workspace layout (floats).
    // partial (128*32*1024 = 4,194,304) ALIASES conv2o (dead after k_mask_pool).
    float* pool1   = ws;                       // 4,194,304  (32,64,64,32)
    float* conv2o  = ws + 4194304;             // 8,388,608  (32,64,64,64)
    float* partial = conv2o;                   // 4,194,304  (128,32,1024) - alias
    float* w2t     = ws + 12582912;            // 18,432
    int*   idx     = (int*)(ws + 12601344);    // 2,048
    float* psum    = ws + 12603392;            // 2,048
    float* abest   = ws + 12605440;            // 32,768 (32,16,64)
    int*   aidx    = (int*)(ws + 12638208);    // 32,768
    float* asum    = ws + 12670976;            // 32,768
    float* dense1o = ws + 12703744;            // 32,768 (32,1024)

    float* logits = out;                       // 320
    float* pool2  = out + 320;                 // 2,097,152  (32,32,32,64)
    float* fcat   = out + 320 + 2097152;       // 64

    k_w2t<<<72, 256, 0, stream>>>(c2w, w2t);
    k_conv1_pool<<<16384, 256, 0, stream>>>(x, c1w, c1b, pool1);
    k_conv2<<<1024, 256, 80384, stream>>>(pool1, w2t, c2b, conv2o);
    dim3 ga(32, 16);
    k_argmax_A<<<ga, 256, 0, stream>>>(conv2o, abest, aidx, asum);
    k_argmax_B<<<32, 64, 0, stream>>>(abest, aidx, asum, idx, psum);
    k_mask_pool<<<8192, 256, 0, stream>>>(conv2o, idx, pool2);
    dim3 g5(128, 4);
    k_dense1_partial<<<g5, 256, 0, stream>>>(pool2, d1w, partial);
    k_dense1_reduce<<<128, 256, 0, stream>>>(partial, d1b, dense1o);
    k_dense2<<<320, 64, 0, stream>>>(dense1o, d2w, d2b, logits);
    k_filter_cat<<<1, 64, 0, stream>>>(psum, labels, fcat);
}